// Round 2
// baseline (559.822 us; speedup 1.0000x reference)
//
#include <hip/hip_runtime.h>
#include <math.h>

// ChebConv GNN: N=50000 nodes, E=800000 edges, F=H=64, C=10.
//   deg[i] = #edges with src==i ; dis = deg>0 ? rsqrt(deg) : 0
//   h   = relu(x @ W1_0 + b1)
//   lap[dst] = sum_e -(dis[src]*dis[dst]) * h[src]   (CSR gather, fused into fused2)
//   h2  = relu(h @ W2_0 + lap @ W2_1 + b2)
//   out = log_softmax((h2 + h) @ Wl + bl)

// Count src-degree (float, for rsqrt) and dst-degree (int, for CSR).
__global__ __launch_bounds__(256) void deg_cnt_kernel(const int* __restrict__ ei,
                                                      float* __restrict__ degS,
                                                      int* __restrict__ cntD, int E) {
    int e = blockIdx.x * blockDim.x + threadIdx.x;
    if (e < E) {
        atomicAdd(&degS[ei[e]], 1.0f);
        atomicAdd(&cntD[ei[E + e]], 1);
    }
}

__global__ __launch_bounds__(256) void dis_kernel(float* __restrict__ deg, int n) {
    int i = blockIdx.x * blockDim.x + threadIdx.x;
    if (i < n) {
        float d = deg[i];
        deg[i] = (d > 0.0f) ? rsqrtf(d) : 0.0f;
    }
}

// Exclusive prefix sum of cntD[n] -> rowptr[n+1]. Single block, 1024 threads.
__global__ __launch_bounds__(1024) void scan_kernel(const int* __restrict__ cnt,
                                                    int* __restrict__ rowptr, int n) {
    __shared__ int wsum[16];
    int t = threadIdx.x;
    int lane = t & 63, wv = t >> 6;
    int chunk = (n + 1023) / 1024;
    int begin = t * chunk;
    int end = begin + chunk; if (end > n) end = n;
    int s = 0;
    for (int i = begin; i < end && i >= 0; ++i) s += cnt[i];
    // inclusive scan within wave
    int v = s;
#pragma unroll
    for (int d = 1; d < 64; d <<= 1) {
        int u = __shfl_up(v, d);
        if (lane >= d) v += u;
    }
    if (lane == 63) wsum[wv] = v;
    __syncthreads();
    if (wv == 0 && lane < 16) {
        int u = wsum[lane];
#pragma unroll
        for (int d = 1; d < 16; d <<= 1) {
            int uu = __shfl_up(u, d);
            if (lane >= d) u += uu;
        }
        wsum[lane] = u;
    }
    __syncthreads();
    int base = (wv > 0 ? wsum[wv - 1] : 0) + (v - s);  // exclusive prefix of chunk
    int run = base;
    for (int i = begin; i < end; ++i) {
        rowptr[i] = run;
        run += cnt[i];
    }
    if (t == 1023) rowptr[n] = wsum[15];
}

// csr[rowptr[dst] + pos] = src, pos via per-dst cursor.
__global__ __launch_bounds__(256) void fill_kernel(const int* __restrict__ ei,
                                                   const int* __restrict__ rowptr,
                                                   int* __restrict__ cursor,
                                                   int* __restrict__ csr, int E) {
    int e = blockIdx.x * blockDim.x + threadIdx.x;
    if (e < E) {
        int d = ei[E + e];
        int pos = atomicAdd(&cursor[d], 1);
        csr[rowptr[d] + pos] = ei[e];
    }
}

// h = relu(x @ W + b), x:[n,64], W:[64,64]. 1 wave = 1 row, lane = out col.
__global__ __launch_bounds__(256) void gemm1_kernel(const float* __restrict__ x,
                                                    const float* __restrict__ W,
                                                    const float* __restrict__ b,
                                                    float* __restrict__ h, int n) {
    __shared__ float sW[64 * 64];
    int tid = threadIdx.x;
    for (int i = tid; i < 64 * 64; i += 256) sW[i] = W[i];
    __syncthreads();
    int wv = tid >> 6, c = tid & 63;
    float bc = b[c];
    int row0 = blockIdx.x * 32 + wv * 8;
    for (int i = 0; i < 8; ++i) {
        int row = row0 + i;
        if (row >= n) break;
        float xv = x[(size_t)row * 64 + c];
        float acc = bc;
#pragma unroll
        for (int k = 0; k < 64; ++k)
            acc += __shfl(xv, k) * sW[k * 64 + c];
        h[(size_t)row * 64 + c] = fmaxf(acc, 0.0f);
    }
}

// Fused: lap gather + h2 = relu(h@W20 + lap@W21 + b2); out = log_softmax((h2+h)@Wl+bl)
__global__ __launch_bounds__(256) void fused2_kernel(const float* __restrict__ h,
                                                     const int* __restrict__ rowptr,
                                                     const int* __restrict__ csr,
                                                     const float* __restrict__ dis,
                                                     const float* __restrict__ W20,
                                                     const float* __restrict__ W21,
                                                     const float* __restrict__ b2,
                                                     const float* __restrict__ Wl,
                                                     const float* __restrict__ bl,
                                                     float* __restrict__ out, int n) {
    __shared__ float sW20[64 * 64];
    __shared__ float sW21[64 * 64];
    __shared__ float sWl[64 * 10];
    int tid = threadIdx.x;
    for (int i = tid; i < 64 * 64; i += 256) {
        sW20[i] = W20[i];
        sW21[i] = W21[i];
    }
    for (int i = tid; i < 64 * 10; i += 256) sWl[i] = Wl[i];
    __syncthreads();
    int wv = tid >> 6, c = tid & 63;
    float b2c = b2[c];
    int row0 = blockIdx.x * 32 + wv * 8;
    for (int i = 0; i < 8; ++i) {
        int row = row0 + i;
        if (row >= n) break;

        // ---- gather lap row into registers ----
        float lv = 0.0f;
        float disd = dis[row];
        int rs = rowptr[row], re = rowptr[row + 1];
        for (int j0 = rs; j0 < re; j0 += 64) {
            int m = re - j0; if (m > 64) m = 64;
            int idx = (c < m) ? csr[j0 + c] : 0;
            float dsl = (c < m) ? dis[idx] : 0.0f;
            for (int k = 0; k < m; ++k) {
                int s = __shfl(idx, k);
                float diss = __shfl(dsl, k);
                lv -= (disd * diss) * h[(size_t)s * 64 + c];
            }
        }

        float hv = h[(size_t)row * 64 + c];
        float acc = b2c;
#pragma unroll
        for (int k = 0; k < 64; ++k) {
            acc += __shfl(hv, k) * sW20[k * 64 + c];
            acc += __shfl(lv, k) * sW21[k * 64 + c];
        }
        float h2 = fmaxf(acc, 0.0f) + hv;  // + residual (x_res = h)

        // out[row][j] = sum_c h2[c]*Wl[c][j] + bl[j], then log_softmax over j
        float m = -1e30f;
        float myout = 0.0f;
#pragma unroll
        for (int j = 0; j < 10; ++j) {
            float p = h2 * sWl[c * 10 + j];
#pragma unroll
            for (int mk = 1; mk < 64; mk <<= 1) p += __shfl_xor(p, mk);
            p += bl[j];
            if (c == j) myout = p;
            m = fmaxf(m, p);  // wave-uniform after butterfly
        }
        float ev = (c < 10) ? expf(myout - m) : 0.0f;
#pragma unroll
        for (int mk = 1; mk < 64; mk <<= 1) ev += __shfl_xor(ev, mk);
        if (c < 10) out[(size_t)row * 10 + c] = myout - m - logf(ev);
    }
}

extern "C" void kernel_launch(void* const* d_in, const int* in_sizes, int n_in,
                              void* d_out, int out_size, void* d_ws, size_t ws_size,
                              hipStream_t stream) {
    const float* x   = (const float*)d_in[0];
    const int*   ei  = (const int*)d_in[1];
    const float* W1  = (const float*)d_in[2];
    const float* b1  = (const float*)d_in[3];
    const float* W20 = (const float*)d_in[4];
    const float* W21 = (const float*)d_in[5];
    const float* b2  = (const float*)d_in[6];
    const float* Wl  = (const float*)d_in[7];
    const float* bl  = (const float*)d_in[8];
    float* out = (float*)d_out;

    int n = in_sizes[0] / 64;   // 50000
    int E = in_sizes[1] / 2;    // 800000

    char* ws = (char*)d_ws;
    size_t off = 0;
    auto alloc = [&](size_t bytes) {
        void* p = ws + off;
        off = (off + bytes + 255) & ~(size_t)255;
        return p;
    };
    float* degS  = (float*)alloc((size_t)n * 4);        // -> dis in place
    int* cntD    = (int*)alloc((size_t)n * 4);
    int* rowptr  = (int*)alloc((size_t)(n + 1) * 4);
    int* cursor  = (int*)alloc((size_t)n * 4);
    int* csr     = (int*)alloc((size_t)E * 4);
    float* h     = (float*)alloc((size_t)n * 64 * 4);

    hipMemsetAsync(degS, 0, (size_t)n * 4, stream);
    hipMemsetAsync(cntD, 0, (size_t)n * 4, stream);
    hipMemsetAsync(cursor, 0, (size_t)n * 4, stream);

    deg_cnt_kernel<<<(E + 255) / 256, 256, 0, stream>>>(ei, degS, cntD, E);
    dis_kernel<<<(n + 255) / 256, 256, 0, stream>>>(degS, n);
    scan_kernel<<<1, 1024, 0, stream>>>(cntD, rowptr, n);
    fill_kernel<<<(E + 255) / 256, 256, 0, stream>>>(ei, rowptr, cursor, csr, E);
    gemm1_kernel<<<(n + 31) / 32, 256, 0, stream>>>(x, W1, b1, h, n);
    fused2_kernel<<<(n + 31) / 32, 256, 0, stream>>>(h, rowptr, csr, degS, W20, W21,
                                                     b2, Wl, bl, out, n);
}

// Round 3
// 238.551 us; speedup vs baseline: 2.3468x; 2.3468x over previous
//
#include <hip/hip_runtime.h>
#include <math.h>

// ChebConv GNN: N=50000, E=800000, F=H=64, C=10.
//   degS[i] = #edges with src==i ; dis = rsqrt(degS) (0 if 0)
//   h  = relu(x @ W1 + b1)
//   p0 = h @ W20 + b2 ;  g = h @ W21
//   lapg[dst] = sum_e -(dis[src]*dis[dst]) * g[src]     (ELL gather)
//   h2 = relu(p0 + lapg) + h ; out = log_softmax(h2 @ Wl + bl)

#define ELLW 64
#define OVCAP 4096

// ---- build: src-degree + ELL adjacency (dst -> list of src) ----
__global__ __launch_bounds__(256) void build_kernel(const int* __restrict__ ei,
                                                    float* __restrict__ degS,
                                                    int* __restrict__ cntD,
                                                    int* __restrict__ ell,
                                                    int* __restrict__ ovCnt,
                                                    int* __restrict__ ov, int E) {
    int e = blockIdx.x * 256 + threadIdx.x;
    if (e >= E) return;
    int s = ei[e], d = ei[E + e];
    atomicAdd(&degS[s], 1.0f);
    int pos = atomicAdd(&cntD[d], 1);
    if (pos < ELLW) {
        ell[(size_t)d * ELLW + pos] = s;
    } else {
        int o = atomicAdd(ovCnt, 1);
        if (o < OVCAP) { ov[2 * o] = s; ov[2 * o + 1] = d; }
    }
}

__global__ __launch_bounds__(256) void dis_kernel(float* __restrict__ deg, int n) {
    int i = blockIdx.x * 256 + threadIdx.x;
    if (i < n) {
        float d = deg[i];
        deg[i] = (d > 0.0f) ? rsqrtf(d) : 0.0f;
    }
}

// ---- triple GEMM: h = relu(x@W1+b1); p0 = h@W20+b2; g = h@W21 ----
// 64-row tile per block, 256 threads, 4x4 register tile per thread.
__global__ __launch_bounds__(256) void gemm3_kernel(const float* __restrict__ x,
                                                    const float* __restrict__ W1,
                                                    const float* __restrict__ b1,
                                                    const float* __restrict__ W20,
                                                    const float* __restrict__ W21,
                                                    const float* __restrict__ b2,
                                                    float* __restrict__ h,
                                                    float* __restrict__ p0,
                                                    float* __restrict__ g, int n) {
    __shared__ __align__(16) float sA[64][68];   // xT, then hT (k-major)
    __shared__ __align__(16) float sW1[64][64];
    __shared__ __align__(16) float sW20[64][64];
    __shared__ __align__(16) float sW21[64][64];
    int t = threadIdx.x;
    for (int i = t; i < 4096; i += 256) {
        sW1[i >> 6][i & 63] = W1[i];
        sW20[i >> 6][i & 63] = W20[i];
        sW21[i >> 6][i & 63] = W21[i];
    }
    int r0 = blockIdx.x * 64;
    {   // stage x transposed: sA[k][r] = x[r0+r][k]
        int rr0 = t >> 4, k0 = (t & 15) * 4;
        for (int rr = rr0; rr < 64; rr += 16) {
            int grow = r0 + rr;
            float4 v = make_float4(0.f, 0.f, 0.f, 0.f);
            if (grow < n) v = *(const float4*)&x[(size_t)grow * 64 + k0];
            sA[k0][rr] = v.x; sA[k0 + 1][rr] = v.y;
            sA[k0 + 2][rr] = v.z; sA[k0 + 3][rr] = v.w;
        }
    }
    __syncthreads();
    int tr = t >> 4, tc = t & 15;

    // phase 1: h = relu(x @ W1 + b1)
    float acc[4][4] = {};
    for (int k = 0; k < 64; ++k) {
        float4 a = *(const float4*)&sA[k][tr * 4];
        float4 b = *(const float4*)&sW1[k][tc * 4];
        float av[4] = {a.x, a.y, a.z, a.w};
        float bv[4] = {b.x, b.y, b.z, b.w};
#pragma unroll
        for (int i = 0; i < 4; ++i)
#pragma unroll
            for (int j = 0; j < 4; ++j) acc[i][j] = fmaf(av[i], bv[j], acc[i][j]);
    }
    float4 bv1 = *(const float4*)&b1[tc * 4];
    float hv[4][4];
#pragma unroll
    for (int i = 0; i < 4; ++i) {
        hv[i][0] = fmaxf(acc[i][0] + bv1.x, 0.f);
        hv[i][1] = fmaxf(acc[i][1] + bv1.y, 0.f);
        hv[i][2] = fmaxf(acc[i][2] + bv1.z, 0.f);
        hv[i][3] = fmaxf(acc[i][3] + bv1.w, 0.f);
    }
#pragma unroll
    for (int i = 0; i < 4; ++i) {
        int grow = r0 + tr * 4 + i;
        if (grow < n) {
            float4 o = make_float4(hv[i][0], hv[i][1], hv[i][2], hv[i][3]);
            *(float4*)&h[(size_t)grow * 64 + tc * 4] = o;
        }
    }
    __syncthreads();   // all reads of sA(xT) done
    // restage: sA[k][r] = hT
#pragma unroll
    for (int i = 0; i < 4; ++i)
#pragma unroll
        for (int j = 0; j < 4; ++j) sA[tc * 4 + j][tr * 4 + i] = hv[i][j];
    __syncthreads();

    // phase 2: p0 = h@W20 + b2 ; g = h@W21
    float accP[4][4] = {}, accG[4][4] = {};
    for (int k = 0; k < 64; ++k) {
        float4 a = *(const float4*)&sA[k][tr * 4];
        float4 bp = *(const float4*)&sW20[k][tc * 4];
        float4 bg = *(const float4*)&sW21[k][tc * 4];
        float av[4] = {a.x, a.y, a.z, a.w};
        float bpv[4] = {bp.x, bp.y, bp.z, bp.w};
        float bgv[4] = {bg.x, bg.y, bg.z, bg.w};
#pragma unroll
        for (int i = 0; i < 4; ++i)
#pragma unroll
            for (int j = 0; j < 4; ++j) {
                accP[i][j] = fmaf(av[i], bpv[j], accP[i][j]);
                accG[i][j] = fmaf(av[i], bgv[j], accG[i][j]);
            }
    }
    float4 bv2 = *(const float4*)&b2[tc * 4];
#pragma unroll
    for (int i = 0; i < 4; ++i) {
        int grow = r0 + tr * 4 + i;
        if (grow < n) {
            float4 op = make_float4(accP[i][0] + bv2.x, accP[i][1] + bv2.y,
                                    accP[i][2] + bv2.z, accP[i][3] + bv2.w);
            float4 og = make_float4(accG[i][0], accG[i][1], accG[i][2], accG[i][3]);
            *(float4*)&p0[(size_t)grow * 64 + tc * 4] = op;
            *(float4*)&g[(size_t)grow * 64 + tc * 4] = og;
        }
    }
}

// ---- gather: lapg[row] = -dis[row] * sum_k dis[src_k] * g[src_k] ----
// 1 wave per row, no LDS, 4 independent accumulators for ILP.
__global__ __launch_bounds__(256) void gather_kernel(const int* __restrict__ ell,
                                                     const int* __restrict__ cntD,
                                                     const float* __restrict__ dis,
                                                     const float* __restrict__ g,
                                                     float* __restrict__ lapg, int n) {
    int c = threadIdx.x & 63;
    int row = blockIdx.x * 4 + (threadIdx.x >> 6);
    if (row >= n) return;
    int m = cntD[row]; if (m > ELLW) m = ELLW;
    int idx = ell[(size_t)row * ELLW + c];
    if (c >= m) idx = 0;           // poison guard
    float dsl = dis[idx];
    float disd = dis[row];
    float a0 = 0.f, a1 = 0.f, a2 = 0.f, a3 = 0.f;
    int k = 0;
    for (; k + 4 <= m; k += 4) {
        int s0 = __shfl(idx, k), s1 = __shfl(idx, k + 1);
        int s2 = __shfl(idx, k + 2), s3 = __shfl(idx, k + 3);
        float w0 = __shfl(dsl, k), w1 = __shfl(dsl, k + 1);
        float w2 = __shfl(dsl, k + 2), w3 = __shfl(dsl, k + 3);
        a0 = fmaf(w0, g[(size_t)s0 * 64 + c], a0);
        a1 = fmaf(w1, g[(size_t)s1 * 64 + c], a1);
        a2 = fmaf(w2, g[(size_t)s2 * 64 + c], a2);
        a3 = fmaf(w3, g[(size_t)s3 * 64 + c], a3);
    }
    for (; k < m; ++k) {
        int s0 = __shfl(idx, k);
        float w0 = __shfl(dsl, k);
        a0 = fmaf(w0, g[(size_t)s0 * 64 + c], a0);
    }
    lapg[(size_t)row * 64 + c] = -disd * ((a0 + a1) + (a2 + a3));
}

// ---- overflow fixup (runs after gather; normally 0 edges) ----
__global__ __launch_bounds__(256) void ovfix_kernel(const int* __restrict__ ovCnt,
                                                    const int* __restrict__ ov,
                                                    const float* __restrict__ dis,
                                                    const float* __restrict__ g,
                                                    float* __restrict__ lapg) {
    int nov = *ovCnt; if (nov > OVCAP) nov = OVCAP;
    int c = threadIdx.x & 63, wv = threadIdx.x >> 6;
    for (int e = wv; e < nov; e += 4) {
        int s = ov[2 * e], d = ov[2 * e + 1];
        float w = -(dis[s] * dis[d]);
        atomicAdd(&lapg[(size_t)d * 64 + c], w * g[(size_t)s * 64 + c]);
    }
}

// ---- epilogue: h2 = relu(p0+lapg)+h; out = log_softmax(h2@Wl + bl) ----
__global__ __launch_bounds__(256) void fused_out_kernel(const float* __restrict__ h,
                                                        const float* __restrict__ p0,
                                                        const float* __restrict__ lapg,
                                                        const float* __restrict__ Wl,
                                                        const float* __restrict__ bl,
                                                        float* __restrict__ out, int n) {
    __shared__ __align__(16) float so[64][68];
    __shared__ __align__(16) float sWlT[10][68];
    __shared__ float sout[64][12];
    int t = threadIdx.x;
    for (int i = t; i < 640; i += 256) sWlT[i % 10][i / 10] = Wl[i];
    int r0 = blockIdx.x * 64;
    for (int v = t; v < 1024; v += 256) {       // v-th float4 of the 64x64 tile
        int row = v >> 4, c4 = (v & 15) * 4;
        int grow = r0 + row;
        float4 o = make_float4(0.f, 0.f, 0.f, 0.f);
        if (grow < n) {
            float4 pv = *(const float4*)&p0[(size_t)grow * 64 + c4];
            float4 lv = *(const float4*)&lapg[(size_t)grow * 64 + c4];
            float4 hv = *(const float4*)&h[(size_t)grow * 64 + c4];
            o.x = fmaxf(pv.x + lv.x, 0.f) + hv.x;
            o.y = fmaxf(pv.y + lv.y, 0.f) + hv.y;
            o.z = fmaxf(pv.z + lv.z, 0.f) + hv.z;
            o.w = fmaxf(pv.w + lv.w, 0.f) + hv.w;
        }
        *(float4*)&so[row][c4] = o;
    }
    __syncthreads();
    for (int j = t; j < 640; j += 256) {        // 64 rows x 10 classes
        int r = j / 10, c = j % 10;
        float acc = bl[c];
#pragma unroll
        for (int k0 = 0; k0 < 64; k0 += 4) {
            float4 a = *(const float4*)&so[r][k0];
            float4 b = *(const float4*)&sWlT[c][k0];
            acc = fmaf(a.x, b.x, acc);
            acc = fmaf(a.y, b.y, acc);
            acc = fmaf(a.z, b.z, acc);
            acc = fmaf(a.w, b.w, acc);
        }
        sout[r][c] = acc;
    }
    __syncthreads();
    int lane16 = t & 15, rb = t >> 4;
    for (int r = rb; r < 64; r += 16) {
        float v = (lane16 < 10) ? sout[r][lane16] : -1e30f;
        float m = v;
#pragma unroll
        for (int d = 1; d < 16; d <<= 1) m = fmaxf(m, __shfl_xor(m, d, 16));
        float e = (lane16 < 10) ? expf(v - m) : 0.f;
        float ssum = e;
#pragma unroll
        for (int d = 1; d < 16; d <<= 1) ssum += __shfl_xor(ssum, d, 16);
        int grow = r0 + r;
        if (grow < n && lane16 < 10)
            out[(size_t)grow * 10 + lane16] = v - m - logf(ssum);
    }
}

extern "C" void kernel_launch(void* const* d_in, const int* in_sizes, int n_in,
                              void* d_out, int out_size, void* d_ws, size_t ws_size,
                              hipStream_t stream) {
    const float* x   = (const float*)d_in[0];
    const int*   ei  = (const int*)d_in[1];
    const float* W1  = (const float*)d_in[2];
    const float* b1  = (const float*)d_in[3];
    const float* W20 = (const float*)d_in[4];
    const float* W21 = (const float*)d_in[5];
    const float* b2  = (const float*)d_in[6];
    const float* Wl  = (const float*)d_in[7];
    const float* bl  = (const float*)d_in[8];
    float* out = (float*)d_out;

    int n = in_sizes[0] / 64;   // 50000
    int E = in_sizes[1] / 2;    // 800000

    char* ws = (char*)d_ws;
    size_t off = 0;
    auto alloc = [&](size_t bytes) {
        void* p = ws + off;
        off = (off + bytes + 255) & ~(size_t)255;
        return p;
    };
    float* degS = (float*)alloc((size_t)n * 4);          // -> dis in place
    int*   cntD = (int*)alloc((size_t)n * 4);
    int*   ovCnt = (int*)alloc(256);
    int*   ov   = (int*)alloc((size_t)OVCAP * 8);
    int*   ell  = (int*)alloc((size_t)n * ELLW * 4);
    float* h    = (float*)alloc((size_t)n * 64 * 4);
    float* p0   = (float*)alloc((size_t)n * 64 * 4);
    float* g    = (float*)alloc((size_t)n * 64 * 4);
    float* lapg = (float*)alloc((size_t)n * 64 * 4);

    hipMemsetAsync(degS, 0, (size_t)n * 4, stream);
    hipMemsetAsync(cntD, 0, (size_t)n * 4, stream);
    hipMemsetAsync(ovCnt, 0, 4, stream);

    build_kernel<<<(E + 255) / 256, 256, 0, stream>>>(ei, degS, cntD, ell, ovCnt, ov, E);
    dis_kernel<<<(n + 255) / 256, 256, 0, stream>>>(degS, n);
    gemm3_kernel<<<(n + 63) / 64, 256, 0, stream>>>(x, W1, b1, W20, W21, b2, h, p0, g, n);
    gather_kernel<<<(n + 3) / 4, 256, 0, stream>>>(ell, cntD, degS, g, lapg, n);
    ovfix_kernel<<<1, 256, 0, stream>>>(ovCnt, ov, degS, g, lapg);
    fused_out_kernel<<<(n + 63) / 64, 256, 0, stream>>>(h, p0, lapg, Wl, bl, out, n);
}